// Round 4
// baseline (229.750 us; speedup 1.0000x reference)
//
#include <hip/hip_runtime.h>
#include <hip/hip_bf16.h>

#define HID 64
#define BLOCK 256

typedef short short8 __attribute__((ext_vector_type(8)));
typedef float floatx4 __attribute__((ext_vector_type(4)));

// load 8 consecutive fp32, convert to bf16 short8 via packed RNE cvt
__device__ __forceinline__ short8 cvt8(const float* __restrict__ p) {
    const float4 f0 = *(const float4*)p;
    const float4 f1 = *(const float4*)(p + 4);
    union { __hip_bfloat162 h[4]; short8 s; } r;
    r.h[0] = __float22bfloat162_rn(make_float2(f0.x, f0.y));
    r.h[1] = __float22bfloat162_rn(make_float2(f0.z, f0.w));
    r.h[2] = __float22bfloat162_rn(make_float2(f1.x, f1.y));
    r.h[3] = __float22bfloat162_rn(make_float2(f1.z, f1.w));
    return r.s;
}

__global__ __launch_bounds__(BLOCK) void moe_line(
    const float* __restrict__ x,
    const float* __restrict__ W,
    const int* __restrict__ mod,
    float* __restrict__ out)
{
    const int tid  = threadIdx.x;
    const int wave = tid >> 6;
    const int lane = tid & 63;
    const int r15  = lane & 15;      // token index within 16-token tile
    const int kg   = lane >> 4;      // k-group 0..3

    const int base = blockIdx.x * 64;   // 64 tokens per block

    // ---- issue ALL x-row loads first (16 float4 pairs), then mod, then W ----
    // B-fragments = x rows; lane holds x[token][kg*8..+8) (kc=0) and +32 (kc=1)
    short8 xb[4][2];
    int m[4];
#pragma unroll
    for (int mt = 0; mt < 4; ++mt) {
        const int token = base + mt * 16 + r15;
        const float* xp = x + (size_t)token * HID + kg * 8;
        xb[mt][0] = cvt8(xp);
        xb[mt][1] = cvt8(xp + 32);
        m[mt] = mod[token];
    }

    // A-fragments = W rows (this wave's 16 output cols), all 3 modalities
    short8 wa[3][2];
#pragma unroll
    for (int mm = 0; mm < 3; ++mm) {
        const float* wp = W + (size_t)mm * HID * HID
                          + (size_t)(wave * 16 + r15) * HID + kg * 8;
        wa[mm][0] = cvt8(wp);
        wa[mm][1] = cvt8(wp + 32);
    }

    // ---- compute + store, straight-line ----
#pragma unroll
    for (int mt = 0; mt < 4; ++mt) {
        floatx4 a0 = {0.f, 0.f, 0.f, 0.f};
        floatx4 a1 = {0.f, 0.f, 0.f, 0.f};
        floatx4 a2 = {0.f, 0.f, 0.f, 0.f};
        a0 = __builtin_amdgcn_mfma_f32_16x16x32_bf16(wa[0][0], xb[mt][0], a0, 0, 0, 0);
        a0 = __builtin_amdgcn_mfma_f32_16x16x32_bf16(wa[0][1], xb[mt][1], a0, 0, 0, 0);
        a1 = __builtin_amdgcn_mfma_f32_16x16x32_bf16(wa[1][0], xb[mt][0], a1, 0, 0, 0);
        a1 = __builtin_amdgcn_mfma_f32_16x16x32_bf16(wa[1][1], xb[mt][1], a1, 0, 0, 0);
        a2 = __builtin_amdgcn_mfma_f32_16x16x32_bf16(wa[2][0], xb[mt][0], a2, 0, 0, 0);
        a2 = __builtin_amdgcn_mfma_f32_16x16x32_bf16(wa[2][1], xb[mt][1], a2, 0, 0, 0);

        // lane's 4 outputs all belong to token (D: col=lane&15, row=kg*4+reg)
        const int mk = m[mt];
        const floatx4 v = (mk == 0) ? a0 : ((mk == 1) ? a1 : a2);

        const int token = base + mt * 16 + r15;
        floatx4* dst = (floatx4*)(out + (size_t)token * HID + wave * 16 + kg * 4);
        __builtin_nontemporal_store(v, dst);   // out is never re-read: keep x in L3
    }
}

extern "C" void kernel_launch(void* const* d_in, const int* in_sizes, int n_in,
                              void* d_out, int out_size, void* d_ws, size_t ws_size,
                              hipStream_t stream) {
    const float* x   = (const float*)d_in[0];
    const float* W   = (const float*)d_in[1];
    const int*   mod = (const int*)d_in[2];
    float*       out = (float*)d_out;

    const int n      = in_sizes[0] / HID;   // tokens (1<<20)
    const int blocks = n / 64;              // 16384

    moe_line<<<blocks, BLOCK, 0, stream>>>(x, W, mod, out);
}

// Round 5
// 122.518 us; speedup vs baseline: 1.8752x; 1.8752x over previous
//
#include <hip/hip_runtime.h>
#include <hip/hip_bf16.h>

#define HID   64
#define BLOCK 256
#define GPB   8                      // 64-token tiles per block -> 2048 blocks

typedef short short8 __attribute__((ext_vector_type(8)));
typedef float floatx4 __attribute__((ext_vector_type(4)));

// two float4 -> bf16 short8 via packed RNE cvt
__device__ __forceinline__ short8 cvt8f(float4 f0, float4 f1) {
    union { __hip_bfloat162 h[4]; short8 s; } r;
    r.h[0] = __float22bfloat162_rn(make_float2(f0.x, f0.y));
    r.h[1] = __float22bfloat162_rn(make_float2(f0.z, f0.w));
    r.h[2] = __float22bfloat162_rn(make_float2(f1.x, f1.y));
    r.h[3] = __float22bfloat162_rn(make_float2(f1.z, f1.w));
    return r.s;
}

__device__ __forceinline__ void gload_lds16(const float* g, float* l) {
    __builtin_amdgcn_global_load_lds(
        (const __attribute__((address_space(1))) void*)g,
        (__attribute__((address_space(3))) void*)l,
        16, 0, 0);
}

__global__ __launch_bounds__(BLOCK) void moe_pipe(
    const float* __restrict__ x,
    const float* __restrict__ W,
    const int* __restrict__ mod,
    float* __restrict__ out)
{
    // [buf][chunk 0..15][lane 0..63][4 floats] -- consumption-order layout:
    // chunk c = mt*4 + kc*2 + half; slot (c,lane) holds
    // x[orig + mt*16 + (lane&15)][ (lane>>4)*8 + kc*32 + half*4 .. +4 )
    __shared__ float sbuf[2][16 * 256];     // 2 x 16 KB

    const int tid  = threadIdx.x;
    const int wave = tid >> 6;
    const int lane = tid & 63;
    const int r15  = lane & 15;
    const int kg   = lane >> 4;

    const long tok0 = (long)blockIdx.x * (GPB * 64);

    // ---- stage tile 0 first (fire-and-forget), then hoist W fragments ----
    auto STAGE = [&](int g, int b) {
        const long orig = tok0 + (long)g * 64;
#pragma unroll
        for (int i = 0; i < 4; ++i) {
            const int c    = wave * 4 + i;       // mt = wave
            const int kc   = i >> 1;
            const int half = i & 1;
            const float* src = x + (orig + wave * 16 + r15) * HID
                                 + kg * 8 + kc * 32 + half * 4;
            gload_lds16(src, &sbuf[b][c * 256]); // uniform base; lane scatters +lane*16B
        }
    };

    STAGE(0, 0);

    // A-fragments = W rows (this wave's 16 output cols), all 3 modalities
    short8 wa[3][2];
#pragma unroll
    for (int mm = 0; mm < 3; ++mm) {
        const float* wp = W + (size_t)mm * HID * HID
                          + (size_t)(wave * 16 + r15) * HID + kg * 8;
        wa[mm][0] = cvt8f(*(const float4*)wp,        *(const float4*)(wp + 4));
        wa[mm][1] = cvt8f(*(const float4*)(wp + 32), *(const float4*)(wp + 36));
    }

    asm volatile("s_waitcnt vmcnt(0)" ::: "memory");
    __builtin_amdgcn_s_barrier();
    __builtin_amdgcn_sched_barrier(0);

    int cur = 0;
#pragma unroll 1
    for (int g = 0; g < GPB; ++g) {
        if (g + 1 < GPB) STAGE(g + 1, cur ^ 1);   // prefetch next tile into other buffer

        const long orig = tok0 + (long)g * 64;
#pragma unroll
        for (int mt = 0; mt < 4; ++mt) {
            const long token = orig + mt * 16 + r15;
            const int  m     = mod[token];

            // B-fragments from LDS: stride-1 ds_read_b128, conflict-free
            const float4 lo0 = *(const float4*)&sbuf[cur][(mt * 4 + 0) * 256 + lane * 4];
            const float4 hi0 = *(const float4*)&sbuf[cur][(mt * 4 + 1) * 256 + lane * 4];
            const float4 lo1 = *(const float4*)&sbuf[cur][(mt * 4 + 2) * 256 + lane * 4];
            const float4 hi1 = *(const float4*)&sbuf[cur][(mt * 4 + 3) * 256 + lane * 4];
            const short8 xb0 = cvt8f(lo0, hi0);
            const short8 xb1 = cvt8f(lo1, hi1);

            floatx4 a0 = {0.f, 0.f, 0.f, 0.f};
            floatx4 a1 = {0.f, 0.f, 0.f, 0.f};
            floatx4 a2 = {0.f, 0.f, 0.f, 0.f};
            a0 = __builtin_amdgcn_mfma_f32_16x16x32_bf16(wa[0][0], xb0, a0, 0, 0, 0);
            a0 = __builtin_amdgcn_mfma_f32_16x16x32_bf16(wa[0][1], xb1, a0, 0, 0, 0);
            a1 = __builtin_amdgcn_mfma_f32_16x16x32_bf16(wa[1][0], xb0, a1, 0, 0, 0);
            a1 = __builtin_amdgcn_mfma_f32_16x16x32_bf16(wa[1][1], xb1, a1, 0, 0, 0);
            a2 = __builtin_amdgcn_mfma_f32_16x16x32_bf16(wa[2][0], xb0, a2, 0, 0, 0);
            a2 = __builtin_amdgcn_mfma_f32_16x16x32_bf16(wa[2][1], xb1, a2, 0, 0, 0);

            const floatx4 v = (m == 0) ? a0 : ((m == 1) ? a1 : a2);

            // lane's 4 outputs all belong to `token`: one dwordx4 (regular store)
            *(floatx4*)(out + token * HID + wave * 16 + kg * 4) = v;
        }

        if (g + 1 < GPB) {
            // counted drain: youngest 4 = this iter's stores; everything older
            // (incl. next tile's 4 stage loads) must be complete before flip.
            asm volatile("s_waitcnt vmcnt(4)" ::: "memory");
            __builtin_amdgcn_s_barrier();
            __builtin_amdgcn_sched_barrier(0);
        }
        cur ^= 1;
    }
}

extern "C" void kernel_launch(void* const* d_in, const int* in_sizes, int n_in,
                              void* d_out, int out_size, void* d_ws, size_t ws_size,
                              hipStream_t stream) {
    const float* x   = (const float*)d_in[0];
    const float* W   = (const float*)d_in[1];
    const int*   mod = (const int*)d_in[2];
    float*       out = (float*)d_out;

    const int n      = in_sizes[0] / HID;     // tokens (1<<20)
    const int blocks = n / (GPB * 64);        // 2048

    moe_pipe<<<blocks, BLOCK, 0, stream>>>(x, W, mod, out);
}